// Round 2
// 690.460 us; speedup vs baseline: 1.1773x; 1.1773x over previous
//
#include <hip/hip_runtime.h>
#include <math.h>

#define B_ 256
#define N_ 200
#define D_ 128
#define H_ 8
#define KD_ 16
#define L_ 3
#define FF_ 512
#define ROWS (B_*N_)          // 51200
#define BND (ROWS*D_)         // 6,553,600

typedef __bf16 bf16x8 __attribute__((ext_vector_type(8)));
typedef float f32x4 __attribute__((ext_vector_type(4)));
typedef _Float16 h16x2 __attribute__((ext_vector_type(2)));
typedef _Float16 f16x4 __attribute__((ext_vector_type(4)));

__device__ __forceinline__ ushort f2bf(float f) {
  union { float f; unsigned u; } v; v.f = f;
  unsigned r = v.u + 0x7fffu + ((v.u >> 16) & 1u);
  return (ushort)(r >> 16);
}
__device__ __forceinline__ float bf2f(ushort h) {
  union { unsigned u; float f; } v; v.u = ((unsigned)h) << 16; return v.f;
}
__device__ __forceinline__ void split2(float f, ushort& hi, ushort& lo) {
  hi = f2bf(f);
  lo = f2bf(f - bf2f(hi));
}

// ---------------- embed: h = x @ Wemb + bemb -> hp fp32 + hi/lo bf16 ----------------
__global__ __launch_bounds__(256) void embed_kernel(const float* __restrict__ x,
    const float* __restrict__ Wemb, const float* __restrict__ bemb,
    float* __restrict__ hp, ushort* __restrict__ hhi, ushort* __restrict__ hlo)
{
  int i4 = blockIdx.x * 256 + threadIdx.x;   // ROWS*32 float4s
  int r  = i4 >> 5, c4 = i4 & 31;
  float x0 = x[2*r], x1 = x[2*r + 1];
  const float4 w0 = ((const float4*)Wemb)[c4];
  const float4 w1 = ((const float4*)Wemb)[32 + c4];
  const float4 bb = ((const float4*)bemb)[c4];
  float o[4];
  o[0] = fmaf(x0, w0.x, fmaf(x1, w1.x, bb.x));
  o[1] = fmaf(x0, w0.y, fmaf(x1, w1.y, bb.y));
  o[2] = fmaf(x0, w0.z, fmaf(x1, w1.z, bb.z));
  o[3] = fmaf(x0, w0.w, fmaf(x1, w1.w, bb.w));
  float4 of = { o[0], o[1], o[2], o[3] };
  ((float4*)hp)[i4] = of;
  ushort hi[4], lo[4];
#pragma unroll
  for (int k = 0; k < 4; k++) split2(o[k], hi[k], lo[k]);
  uint2 ph, pl;
  ph.x = (uint)hi[0] | ((uint)hi[1] << 16);
  ph.y = (uint)hi[2] | ((uint)hi[3] << 16);
  pl.x = (uint)lo[0] | ((uint)lo[1] << 16);
  pl.y = (uint)lo[2] | ((uint)lo[3] << 16);
  ((uint2*)hhi)[i4] = ph;
  ((uint2*)hlo)[i4] = pl;
}

// ------------- static weight transposes (Wo, W2) -> bf16 hi/lo [N][K] -------------
__global__ __launch_bounds__(256) void t_wo(const float* __restrict__ Wo,
    ushort* __restrict__ dhi, ushort* __restrict__ dlo)
{
  int i = blockIdx.x * 256 + threadIdx.x;     // L*128*128 = 49152 exact
  int l = i / 16384, r = i % 16384;
  int n = r >> 7, k = r & 127;
  int hh = k >> 4, kd = k & 15;
  float w = Wo[l*16384 + hh*2048 + kd*128 + n];
  split2(w, dhi[i], dlo[i]);
}
__global__ __launch_bounds__(256) void t_w2(const float* __restrict__ W2,
    ushort* __restrict__ dhi, ushort* __restrict__ dlo)
{
  int i = blockIdx.x * 256 + threadIdx.x;     // L*128*512 = 196608 exact
  int l = i / 65536, r = i % 65536;
  int d = r >> 9, f = r & 511;
  float w = W2[l*65536 + f*128 + d];
  split2(w, dhi[i], dlo[i]);
}

// ------------- init BN-fold state to identity -------------
__global__ __launch_bounds__(128) void init_scales(float* __restrict__ sc, float* __restrict__ sh)
{
  int c = threadIdx.x;
  sc[c] = 1.f;
  sh[c] = 0.f;
}

// ------------- fold BN into QKV weights (PARALLEL: block=n-row, thread=k) -------------
__global__ __launch_bounds__(128) void fold_qkv(const float* __restrict__ Wq,
    const float* __restrict__ Wk, const float* __restrict__ Wv,
    const float* __restrict__ sc, const float* __restrict__ sh,
    ushort* __restrict__ whi, ushort* __restrict__ wlo, float* __restrict__ bout)
{
  __shared__ float wsum[2];
  int n = blockIdx.x;                     // 0..383
  int k = threadIdx.x;                    // 0..127
  int which = n >> 7, hh = (n >> 4) & 7, kd = n & 15;
  const float* src = (which == 0) ? Wq : (which == 1) ? Wk : Wv;
  float w = src[hh*2048 + k*16 + kd];
  split2(w * sc[k], whi[n*128 + k], wlo[n*128 + k]);   // coalesced writes over k
  float p = sh[k] * w;
#pragma unroll
  for (int d = 1; d < 64; d <<= 1) p += __shfl_xor(p, d);
  if ((k & 63) == 0) wsum[k >> 6] = p;
  __syncthreads();
  if (k == 0) bout[n] = wsum[0] + wsum[1];
}

// ------------- fold BN into W1 (PARALLEL: block=f-row, thread=k) -------------
__global__ __launch_bounds__(128) void fold_w1(const float* __restrict__ W1,
    const float* __restrict__ b1, const float* __restrict__ sc, const float* __restrict__ sh,
    ushort* __restrict__ whi, ushort* __restrict__ wlo, float* __restrict__ bout)
{
  __shared__ float wsum[2];
  int f = blockIdx.x;                     // 0..511
  int k = threadIdx.x;                    // 0..127
  float w = W1[k*512 + f];
  split2(w * sc[k], whi[f*128 + k], wlo[f*128 + k]);
  float p = sh[k] * w;
#pragma unroll
  for (int d = 1; d < 64; d <<= 1) p += __shfl_xor(p, d);
  if ((k & 63) == 0) wsum[k >> 6] = p;
  __syncthreads();
  if (k == 0) bout[f] = b1[f] + wsum[0] + wsum[1];
}

// ---------------- split-bf16 MFMA GEMM: BK=64 XOR-swizzle body + BN-fold epilogue ----------------
template<int K, bool BIAS, bool RELU, bool RESIDBN, bool OUTF32, bool OUTHL, bool STATS>
__global__ __launch_bounds__(256, 2) void gemm_mfma(
    const ushort* __restrict__ Ahi, const ushort* __restrict__ Alo,
    const ushort* __restrict__ Whi, const ushort* __restrict__ Wlo,
    const float* __restrict__ bias,
    const float* __restrict__ residf, const float* __restrict__ rsc, const float* __restrict__ rsh,
    float* __restrict__ Cf, ushort* __restrict__ Chi, ushort* __restrict__ Clo,
    float* __restrict__ psum, float* __restrict__ psq, int Ntot)
{
  __shared__ ushort AhiS[128*64];
  __shared__ ushort AloS[128*64];
  __shared__ ushort BhiS[128*64];
  __shared__ ushort BloS[128*64];
  const int t    = threadIdx.x;
  const int bm   = blockIdx.y * 128;
  const int bn   = blockIdx.x * 128;
  const int lane = t & 63;
  const int w    = t >> 6, wm = w >> 1, wn = w & 1;
  const int quad = lane >> 4, l15 = lane & 15;

  f32x4 acc[4][4];
#pragma unroll
  for (int i = 0; i < 4; i++)
#pragma unroll
    for (int j = 0; j < 4; j++) acc[i][j] = (f32x4){0.f, 0.f, 0.f, 0.f};

  const ushort* AhiB = Ahi + (size_t)bm * K;
  const ushort* AloB = Alo + (size_t)bm * K;
  const ushort* BhiB = Whi + (size_t)bn * K;
  const ushort* BloB = Wlo + (size_t)bn * K;

  for (int k0 = 0; k0 < K; k0 += 64) {
#pragma unroll
    for (int i = 0; i < 4; i++) {
      int idx = i * 256 + t;
      int row = idx >> 3, c = idx & 7;
      int k8  = c ^ (row & 7);
      size_t off = (size_t)row * K + k0 + k8 * 8;
      ((uint4*)AhiS)[idx] = *(const uint4*)(AhiB + off);
      ((uint4*)AloS)[idx] = *(const uint4*)(AloB + off);
      ((uint4*)BhiS)[idx] = *(const uint4*)(BhiB + off);
      ((uint4*)BloS)[idx] = *(const uint4*)(BloB + off);
    }
    __syncthreads();
#pragma unroll
    for (int ks = 0; ks < 2; ks++) {
      bf16x8 ah[4], al[4], bh[4], bl[4];
#pragma unroll
      for (int i = 0; i < 4; i++) {
        int row = wm * 64 + i * 16 + l15;
        int k8  = ks * 4 + quad;
        int ci  = k8 ^ (row & 7);
        ah[i] = ((const bf16x8*)AhiS)[row * 8 + ci];
        al[i] = ((const bf16x8*)AloS)[row * 8 + ci];
        int nrow = wn * 64 + i * 16 + l15;
        int cj   = k8 ^ (nrow & 7);
        bh[i] = ((const bf16x8*)BhiS)[nrow * 8 + cj];
        bl[i] = ((const bf16x8*)BloS)[nrow * 8 + cj];
      }
#pragma unroll
      for (int i = 0; i < 4; i++)
#pragma unroll
        for (int j = 0; j < 4; j++) {
          acc[i][j] = __builtin_amdgcn_mfma_f32_16x16x32_bf16(al[i], bh[j], acc[i][j], 0, 0, 0);
          acc[i][j] = __builtin_amdgcn_mfma_f32_16x16x32_bf16(ah[i], bl[j], acc[i][j], 0, 0, 0);
          acc[i][j] = __builtin_amdgcn_mfma_f32_16x16x32_bf16(ah[i], bh[j], acc[i][j], 0, 0, 0);
        }
    }
    __syncthreads();
  }

  float bv[4], scv[4], shv[4];
#pragma unroll
  for (int j = 0; j < 4; j++) {
    int col = bn + wn*64 + j*16 + l15;
    if (BIAS)    bv[j]  = bias[col];
    if (RESIDBN) { scv[j] = rsc[col]; shv[j] = rsh[col]; }
  }
  float sj[4] = {0.f,0.f,0.f,0.f}, qj[4] = {0.f,0.f,0.f,0.f};
#pragma unroll
  for (int i = 0; i < 4; i++) {
#pragma unroll
    for (int r = 0; r < 4; r++) {
      int row = bm + wm*64 + i*16 + quad*4 + r;
#pragma unroll
      for (int j = 0; j < 4; j++) {
        int col = bn + wn*64 + j*16 + l15;
        float v = acc[i][j][r];
        if (BIAS)    v += bv[j];
        if (RELU)    v = fmaxf(v, 0.f);
        if (RESIDBN) v += fmaf(residf[(size_t)row * Ntot + col], scv[j], shv[j]);
        if (OUTF32)  Cf[(size_t)row * Ntot + col] = v;
        if (OUTHL) {
          ushort hi, lo;
          split2(v, hi, lo);
          Chi[(size_t)row * Ntot + col] = hi;
          Clo[(size_t)row * Ntot + col] = lo;
        }
        if (STATS) { sj[j] += v; qj[j] = fmaf(v, v, qj[j]); }
      }
    }
  }
  if (STATS) {
#pragma unroll
    for (int j = 0; j < 4; j++) {
      sj[j] += __shfl_xor(sj[j], 16); sj[j] += __shfl_xor(sj[j], 32);
      qj[j] += __shfl_xor(qj[j], 16); qj[j] += __shfl_xor(qj[j], 32);
    }
    float* ssum = (float*)AhiS;     // safe: k-loop ended with barrier
    float* ssq  = ssum + 128;
    if (t < 128) { ssum[t] = 0.f; ssq[t] = 0.f; }
    __syncthreads();
    if (quad == 0) {
#pragma unroll
      for (int j = 0; j < 4; j++) {
        int col = wn*64 + j*16 + l15;
        atomicAdd(&ssum[col], sj[j]);
        atomicAdd(&ssq[col],  qj[j]);
      }
    }
    __syncthreads();
    if (t < 128) {
      psum[blockIdx.y * 128 + t] = ssum[t];
      psq [blockIdx.y * 128 + t] = ssq[t];
    }
  }
}

// ---------------- MFMA fused attention ----------------
// Block = one (b,h). S^T = K·Q^T via mfma_f32_16x16x16f16 so that the C-layout
// of S^T (row=key=g*4+r, col=q=l15) IS the B-frag layout P^T needs for
// O^T = V^T·P^T: softmax -> PV with zero cross-lane movement.
// Full 208-key score row lives in 13 C tiles (52 VGPR) -> one-shot softmax
// (2 shfl_xor for max, 2 for sum). V split hi/lo fp16 for ~fp32 PV precision.
// O^T C-layout: lane holds row q=l15, cols kd=g*4+r -> contiguous 8B stores.
__global__ __launch_bounds__(256) void attn_kernel(const float* __restrict__ qkv,
    ushort* __restrict__ Ohi, ushort* __restrict__ Olo)
{
  __shared__ __align__(16) _Float16 Ksh[208*20];    // [key][kd], pitch 20 (bank stagger)
  __shared__ __align__(16) _Float16 VTh[16*216];    // V^T hi [kd][key], pitch 216
  __shared__ __align__(16) _Float16 VTl[16*216];    // V^T lo
  const int b  = blockIdx.x >> 3;
  const int hh = blockIdx.x & 7;
  const int t  = threadIdx.x;
  const float* basep = qkv + (size_t)b * N_ * 384 + hh * 16;

  // ---- stage K as fp16 [208][20]; zero pad rows 200..207 ----
  for (int i = t; i < 208*4; i += 256) {
    int n = i >> 2, c4 = i & 3;
    float4 kv = {0.f, 0.f, 0.f, 0.f};
    if (n < N_) kv = *(const float4*)(basep + n*384 + 128 + c4*4);
    f16x4 kh = { (_Float16)kv.x, (_Float16)kv.y, (_Float16)kv.z, (_Float16)kv.w };
    *(f16x4*)&Ksh[n*20 + c4*4] = kh;
  }
  // ---- stage V^T hi/lo fp16 [16][216]; zero pad cols 200..207 ----
  for (int i = t; i < 16*104; i += 256) {
    int kd = i & 15, n2 = i >> 4;
    int n0 = 2*n2, n1 = n0 + 1;
    float v0 = (n0 < N_) ? basep[n0*384 + 256 + kd] : 0.f;
    float v1 = (n1 < N_) ? basep[n1*384 + 256 + kd] : 0.f;
    _Float16 h0 = (_Float16)v0, h1 = (_Float16)v1;
    _Float16 e0 = (_Float16)(v0 - (float)h0), e1 = (_Float16)(v1 - (float)h1);
    h16x2 hp = { h0, h1 }, lp = { e0, e1 };
    *(h16x2*)&VTh[kd*216 + n0] = hp;
    *(h16x2*)&VTl[kd*216 + n0] = lp;
  }
  __syncthreads();

  const int lane = t & 63;
  const int w    = t >> 6;
  const int l15  = lane & 15;
  const int g    = lane >> 4;
  const float SCL = 0.25f * 1.44269504088896340736f;   // 1/sqrt(KD) * log2(e)

  for (int qt = w; qt < 13; qt += 4) {
    int qr  = qt*16 + l15;                 // query row in [0,208)
    int qrc = qr < N_ ? qr : N_-1;         // clamp pad rows (results discarded)
    float4 qf = *(const float4*)(basep + (size_t)qrc*384 + g*4);
    f16x4 bq = { (_Float16)(qf.x*SCL), (_Float16)(qf.y*SCL),
                 (_Float16)(qf.z*SCL), (_Float16)(qf.w*SCL) };

    // S^T tiles: ct[kt] holds scores for keys kt*16+g*4+r, query q=l15
    f32x4 ct[13];
#pragma unroll
    for (int kt = 0; kt < 13; kt++) {
      f16x4 ak = *(const f16x4*)&Ksh[(kt*16 + l15)*20 + g*4];
      ct[kt] = __builtin_amdgcn_mfma_f32_16x16x16f16(ak, bq, (f32x4){0.f,0.f,0.f,0.f}, 0, 0, 0);
    }
    // mask pad keys (192+g*4+r >= 200)
#pragma unroll
    for (int r = 0; r < 4; r++)
      if (g*4 + r >= 8) ct[12][r] = -1e30f;

    // row max over 13 tiles (two partial chains) then across g groups
    float m0 = -1e30f, m1 = -1e30f;
#pragma unroll
    for (int kt = 0; kt < 13; kt++) {
      m0 = fmaxf(m0, fmaxf(ct[kt][0], ct[kt][1]));
      m1 = fmaxf(m1, fmaxf(ct[kt][2], ct[kt][3]));
    }
    float m = fmaxf(m0, m1);
    m = fmaxf(m, __shfl_xor(m, 16));
    m = fmaxf(m, __shfl_xor(m, 32));

    // exp2 + row sum (4 independent accumulation chains)
    float la0 = 0.f, la1 = 0.f, la2 = 0.f, la3 = 0.f;
#pragma unroll
    for (int kt = 0; kt < 13; kt++) {
      float p0 = __builtin_amdgcn_exp2f(ct[kt][0] - m);
      float p1 = __builtin_amdgcn_exp2f(ct[kt][1] - m);
      float p2 = __builtin_amdgcn_exp2f(ct[kt][2] - m);
      float p3 = __builtin_amdgcn_exp2f(ct[kt][3] - m);
      la0 += p0; la1 += p1; la2 += p2; la3 += p3;
      ct[kt][0] = p0; ct[kt][1] = p1; ct[kt][2] = p2; ct[kt][3] = p3;
    }
    float l = (la0 + la1) + (la2 + la3);
    l += __shfl_xor(l, 16);
    l += __shfl_xor(l, 32);

    // O^T = V^T(hi) P^T + V^T(lo) P^T  — P^T B-frags come straight from ct
    f32x4 och = {0.f,0.f,0.f,0.f}, ocl = {0.f,0.f,0.f,0.f};
#pragma unroll
    for (int kt = 0; kt < 13; kt++) {
      f16x4 pt = { (_Float16)ct[kt][0], (_Float16)ct[kt][1],
                   (_Float16)ct[kt][2], (_Float16)ct[kt][3] };
      f16x4 avh = *(const f16x4*)&VTh[l15*216 + kt*16 + g*4];
      f16x4 avl = *(const f16x4*)&VTl[l15*216 + kt*16 + g*4];
      och = __builtin_amdgcn_mfma_f32_16x16x16f16(avh, pt, och, 0, 0, 0);
      ocl = __builtin_amdgcn_mfma_f32_16x16x16f16(avl, pt, ocl, 0, 0, 0);
    }

    if (qr < N_) {
      float inv = __builtin_amdgcn_rcpf(l);
      ushort hi[4], lo[4];
#pragma unroll
      for (int r = 0; r < 4; r++) {
        float v = (och[r] + ocl[r]) * inv;
        split2(v, hi[r], lo[r]);
      }
      uint2 ph, pl;
      ph.x = (uint)hi[0] | ((uint)hi[1] << 16);
      ph.y = (uint)hi[2] | ((uint)hi[3] << 16);
      pl.x = (uint)lo[0] | ((uint)lo[1] << 16);
      pl.y = (uint)lo[2] | ((uint)lo[3] << 16);
      size_t obase = ((size_t)(b*N_ + qr))*128 + hh*16 + g*4;
      *(uint2*)(Ohi + obase) = ph;
      *(uint2*)(Olo + obase) = pl;
    }
  }
}

// ---------------- BN finalize: PARALLEL (block=channel, wave reduce 400 partials) ----------------
__global__ __launch_bounds__(64) void bn_finalize(const float* __restrict__ psum,
    const float* __restrict__ psq, const float* __restrict__ g,
    const float* __restrict__ bta, float* __restrict__ scale, float* __restrict__ shift)
{
  int c = blockIdx.x;        // 0..127
  int i = threadIdx.x;       // 0..63
  float s = 0.f, q = 0.f;
  for (int r = i; r < 400; r += 64) { s += psum[r*128 + c]; q += psq[r*128 + c]; }
#pragma unroll
  for (int d = 32; d > 0; d >>= 1) { s += __shfl_down(s, d); q += __shfl_down(q, d); }
  if (i == 0) {
    const float invM = 1.f / 51200.f;
    float m  = s * invM;
    float v  = fmaf(q, invM, -m * m);
    float r  = rsqrtf(v + 1e-5f);
    float sc = r * g[c];
    scale[c] = sc;
    shift[c] = fmaf(-m, sc, bta[c]);
  }
}

// ---------------- final BN apply + per-batch mean (fused) ----------------
// One block per batch b; thread d applies scale/shift over n and accumulates mean.
__global__ __launch_bounds__(128) void bn_mean_final(float* __restrict__ hp,
    const float* __restrict__ scale, const float* __restrict__ shift,
    float* __restrict__ mout)
{
  int b = blockIdx.x, d = threadIdx.x;
  float sc = scale[d], sh = shift[d];
  float* p = hp + (size_t)b * N_ * D_ + d;
  float s = 0.f;
  for (int n = 0; n < N_; n++) {
    float v = fmaf(p[n * D_], sc, sh);
    p[n * D_] = v;
    s += v;
  }
  mout[b * D_ + d] = s * (1.f / N_);
}

extern "C" void kernel_launch(void* const* d_in, const int* in_sizes, int n_in,
                              void* d_out, int out_size, void* d_ws, size_t ws_size,
                              hipStream_t stream)
{
  const float* x    = (const float*)d_in[0];
  const float* Wemb = (const float*)d_in[1];
  const float* bemb = (const float*)d_in[2];
  const float* Wq   = (const float*)d_in[3];
  const float* Wk   = (const float*)d_in[4];
  const float* Wv   = (const float*)d_in[5];
  const float* Wo   = (const float*)d_in[6];
  const float* bn1g = (const float*)d_in[7];
  const float* bn1b = (const float*)d_in[8];
  const float* W1   = (const float*)d_in[9];
  const float* b1   = (const float*)d_in[10];
  const float* W2   = (const float*)d_in[11];
  const float* b2   = (const float*)d_in[12];
  const float* bn2g = (const float*)d_in[13];
  const float* bn2b = (const float*)d_in[14];
  float* out = (float*)d_out;

  // rolling pre-BN residual state hp lives in d_out[0:BND]
  float* hp = out;

  char* wsb = (char*)d_ws;
  ushort* h_hi  = (ushort*)wsb;                     // 13,107,200 B
  ushort* h_lo  = (ushort*)(wsb + 13107200);        // 13,107,200 B
  char*   phase = wsb + 26214400;                   // 104,857,600 B union
  float*  qkv   = (float*)phase;                    //   attn: 78,643,200 B fp32
  ushort* hd_hi = (ushort*)(phase + 78643200);      //   attn: 13,107,200 B
  ushort* hd_lo = (ushort*)(phase + 91750400);      //   attn: 13,107,200 B
  ushort* hid_hi = (ushort*)phase;                  //   ffn: 52,428,800 B
  ushort* hid_lo = (ushort*)(phase + 52428800);     //   ffn: 52,428,800 B
  char*   wp    = wsb + 131072000;
  ushort* woT_hi  = (ushort*)wp;                    // 98,304 B
  ushort* woT_lo  = (ushort*)(wp + 98304);          // 98,304 B
  ushort* w2T_hi  = (ushort*)(wp + 196608);         // 393,216 B
  ushort* w2T_lo  = (ushort*)(wp + 589824);         // 393,216 B
  ushort* fqkv_hi = (ushort*)(wp + 983040);         // 98,304 B
  ushort* fqkv_lo = (ushort*)(wp + 1081344);        // 98,304 B
  ushort* fw1_hi  = (ushort*)(wp + 1179648);        // 131,072 B
  ushort* fw1_lo  = (ushort*)(wp + 1310720);        // 131,072 B
  float*  fqkv_b  = (float*)(wp + 1441792);         // 1,536 B
  float*  fw1_b   = (float*)(wp + 1443328);         // 2,048 B
  float*  psum    = (float*)(wp + 1445376);         // 204,800 B
  float*  psq     = (float*)(wp + 1650176);         // 204,800 B
  float*  sc_a    = (float*)(wp + 1854976);
  float*  sh_a    = (float*)(wp + 1855488);
  float*  sc_b    = (float*)(wp + 1856000);
  float*  sh_b    = (float*)(wp + 1856512);

  embed_kernel<<<6400, 256, 0, stream>>>(x, Wemb, bemb, hp, h_hi, h_lo);
  t_wo<<<192, 256, 0, stream>>>(Wo, woT_hi, woT_lo);
  t_w2<<<768, 256, 0, stream>>>(W2, w2T_hi, w2T_lo);
  init_scales<<<1, 128, 0, stream>>>(sc_b, sh_b);

  for (int l = 0; l < L_; l++) {
    // fold BN(prev layer / identity) into QKV weights (parallel, coalesced)
    fold_qkv<<<384, 128, 0, stream>>>(Wq + l*16384, Wk + l*16384, Wv + l*16384,
                                      sc_b, sh_b, fqkv_hi, fqkv_lo, fqkv_b);
    // QKV projection -> qkv fp32 [rows][384]
    gemm_mfma<128, true, false, false, true, false, false><<<dim3(3, 400), 256, 0, stream>>>(
        h_hi, h_lo, fqkv_hi, fqkv_lo, fqkv_b, nullptr, nullptr, nullptr,
        qkv, nullptr, nullptr, nullptr, nullptr, 384);
    // attention -> heads hi/lo
    attn_kernel<<<B_ * H_, 256, 0, stream>>>(qkv, hd_hi, hd_lo);
    // out-proj + BN-folded residual -> hp (h1_pre) fp32 + hi/lo + BN1 stats
    gemm_mfma<128, false, false, true, true, true, true><<<dim3(1, 400), 256, 0, stream>>>(
        hd_hi, hd_lo, woT_hi + l*16384, woT_lo + l*16384, nullptr, hp, sc_b, sh_b,
        hp, h_hi, h_lo, psum, psq, 128);
    bn_finalize<<<128, 64, 0, stream>>>(psum, psq, bn1g + l*128, bn1b + l*128, sc_a, sh_a);
    // fold BN1 into W1 (parallel, coalesced)
    fold_w1<<<512, 128, 0, stream>>>(W1 + l*65536, b1 + l*512, sc_a, sh_a, fw1_hi, fw1_lo, fw1_b);
    // FFN1 + folded bias + relu -> hidden hi/lo
    gemm_mfma<128, true, true, false, false, true, false><<<dim3(4, 400), 256, 0, stream>>>(
        h_hi, h_lo, fw1_hi, fw1_lo, fw1_b, nullptr, nullptr, nullptr,
        nullptr, hid_hi, hid_lo, nullptr, nullptr, 512);
    // FFN2 + bias + BN1-folded residual -> hp (h2_pre) fp32 + hi/lo + BN2 stats
    gemm_mfma<512, true, false, true, true, true, true><<<dim3(1, 400), 256, 0, stream>>>(
        hid_hi, hid_lo, w2T_hi + l*65536, w2T_lo + l*65536, b2 + l*128, hp, sc_a, sh_a,
        hp, h_hi, h_lo, psum, psq, 128);
    bn_finalize<<<128, 64, 0, stream>>>(psum, psq, bn2g + l*128, bn2b + l*128, sc_b, sh_b);
  }

  bn_mean_final<<<B_, 128, 0, stream>>>(hp, sc_b, sh_b, out + BND);
}

// Round 3
// 624.334 us; speedup vs baseline: 1.3019x; 1.1059x over previous
//
#include <hip/hip_runtime.h>
#include <math.h>

#define B_ 256
#define N_ 200
#define D_ 128
#define H_ 8
#define KD_ 16
#define L_ 3
#define FF_ 512
#define ROWS (B_*N_)          // 51200
#define BND (ROWS*D_)         // 6,553,600

typedef float f32x4 __attribute__((ext_vector_type(4)));
typedef _Float16 f16x4 __attribute__((ext_vector_type(4)));
typedef _Float16 f16x8 __attribute__((ext_vector_type(8)));

__device__ __forceinline__ ushort f2h_bits(float f) {
  _Float16 h = (_Float16)f;
  union { _Float16 h; ushort u; } v; v.h = h; return v.u;
}
// fp16 hi/lo split: hi + lo reconstructs f to ~2^-21 relative
__device__ __forceinline__ void splith(float f, ushort& hi, ushort& lo) {
  _Float16 h = (_Float16)f;
  float hf = (float)h;
  _Float16 l = (_Float16)(f - hf);
  union { _Float16 h; ushort u; } a, b; a.h = h; b.h = l;
  hi = a.u; lo = b.u;
}

// ---------------- embed: h = x @ Wemb + bemb -> hp fp32 + hi/lo fp16 ----------------
__global__ __launch_bounds__(256) void embed_kernel(const float* __restrict__ x,
    const float* __restrict__ Wemb, const float* __restrict__ bemb,
    float* __restrict__ hp, ushort* __restrict__ hhi, ushort* __restrict__ hlo)
{
  int i4 = blockIdx.x * 256 + threadIdx.x;   // ROWS*32 float4s
  int r  = i4 >> 5, c4 = i4 & 31;
  float x0 = x[2*r], x1 = x[2*r + 1];
  const float4 w0 = ((const float4*)Wemb)[c4];
  const float4 w1 = ((const float4*)Wemb)[32 + c4];
  const float4 bb = ((const float4*)bemb)[c4];
  float o[4];
  o[0] = fmaf(x0, w0.x, fmaf(x1, w1.x, bb.x));
  o[1] = fmaf(x0, w0.y, fmaf(x1, w1.y, bb.y));
  o[2] = fmaf(x0, w0.z, fmaf(x1, w1.z, bb.z));
  o[3] = fmaf(x0, w0.w, fmaf(x1, w1.w, bb.w));
  float4 of = { o[0], o[1], o[2], o[3] };
  ((float4*)hp)[i4] = of;
  ushort hi[4], lo[4];
#pragma unroll
  for (int k = 0; k < 4; k++) splith(o[k], hi[k], lo[k]);
  uint2 ph, pl;
  ph.x = (uint)hi[0] | ((uint)hi[1] << 16);
  ph.y = (uint)hi[2] | ((uint)hi[3] << 16);
  pl.x = (uint)lo[0] | ((uint)lo[1] << 16);
  pl.y = (uint)lo[2] | ((uint)lo[3] << 16);
  ((uint2*)hhi)[i4] = ph;
  ((uint2*)hlo)[i4] = pl;
}

// ------------- static weight transposes (Wo, W2) -> single fp16 [N][K] -------------
__global__ __launch_bounds__(256) void t_wo(const float* __restrict__ Wo,
    ushort* __restrict__ dh)
{
  int i = blockIdx.x * 256 + threadIdx.x;     // L*128*128 = 49152 exact
  int l = i / 16384, r = i % 16384;
  int n = r >> 7, k = r & 127;
  int hh = k >> 4, kd = k & 15;
  float w = Wo[l*16384 + hh*2048 + kd*128 + n];
  dh[i] = f2h_bits(w);
}
__global__ __launch_bounds__(256) void t_w2(const float* __restrict__ W2,
    ushort* __restrict__ dh)
{
  int i = blockIdx.x * 256 + threadIdx.x;     // L*128*512 = 196608 exact
  int l = i / 65536, r = i % 65536;
  int d = r >> 9, f = r & 511;
  float w = W2[l*65536 + f*128 + d];
  dh[i] = f2h_bits(w);
}

// ------------- init BN-fold state to identity -------------
__global__ __launch_bounds__(128) void init_scales(float* __restrict__ sc, float* __restrict__ sh)
{
  int c = threadIdx.x;
  sc[c] = 1.f;
  sh[c] = 0.f;
}

// ------------- fold BN into QKV weights; Q rows pre-scaled by 0.25*log2(e) -------------
__global__ __launch_bounds__(128) void fold_qkv(const float* __restrict__ Wq,
    const float* __restrict__ Wk, const float* __restrict__ Wv,
    const float* __restrict__ sc, const float* __restrict__ sh,
    ushort* __restrict__ wh, float* __restrict__ bout)
{
  __shared__ float wsum[2];
  int n = blockIdx.x;                     // 0..383
  int k = threadIdx.x;                    // 0..127
  int which = n >> 7, hh = (n >> 4) & 7, kd = n & 15;
  const float* src = (which == 0) ? Wq : (which == 1) ? Wk : Wv;
  float w = src[hh*2048 + k*16 + kd];
  if (which == 0) w *= 0.25f * 1.44269504088896340736f;   // fold 1/sqrt(KD)*log2(e) into Q
  wh[n*128 + k] = f2h_bits(w * sc[k]);
  float p = sh[k] * w;
#pragma unroll
  for (int d = 1; d < 64; d <<= 1) p += __shfl_xor(p, d);
  if ((k & 63) == 0) wsum[k >> 6] = p;
  __syncthreads();
  if (k == 0) bout[n] = wsum[0] + wsum[1];
}

// ------------- fold BN into W1 -------------
__global__ __launch_bounds__(128) void fold_w1(const float* __restrict__ W1,
    const float* __restrict__ b1, const float* __restrict__ sc, const float* __restrict__ sh,
    ushort* __restrict__ wh, float* __restrict__ bout)
{
  __shared__ float wsum[2];
  int f = blockIdx.x;                     // 0..511
  int k = threadIdx.x;                    // 0..127
  float w = W1[k*512 + f];
  wh[f*128 + k] = f2h_bits(w * sc[k]);
  float p = sh[k] * w;
#pragma unroll
  for (int d = 1; d < 64; d <<= 1) p += __shfl_xor(p, d);
  if ((k & 63) == 0) wsum[k >> 6] = p;
  __syncthreads();
  if (k == 0) bout[f] = b1[f] + wsum[0] + wsum[1];
}

// ---------------- fp16 MFMA GEMM: A = hi(/lo) fp16, B = single fp16 ----------------
// ALO: A has a lo-correction array (2 MFMA/acc); else 1 MFMA/acc.
template<int K, bool ALO, bool BIAS, bool RELU, bool RESIDBN,
         bool OUTQKV, bool OUT16, bool OUTHL, bool OUTF32, bool STATS>
__global__ __launch_bounds__(256, 2) void gemm_mfma(
    const ushort* __restrict__ Ahi, const ushort* __restrict__ Alo,
    const ushort* __restrict__ Wh,
    const float* __restrict__ bias,
    const float* __restrict__ residf, const float* __restrict__ rsc, const float* __restrict__ rsh,
    float* __restrict__ Cf, ushort* __restrict__ C16,
    ushort* __restrict__ Chl_hi, ushort* __restrict__ Chl_lo,
    float* __restrict__ psum, float* __restrict__ psq, int Ntot)
{
  __shared__ ushort AhiS[128*64];
  __shared__ ushort AloS[ALO ? 128*64 : 8];
  __shared__ ushort BhS [128*64];
  const int t    = threadIdx.x;
  const int bm   = blockIdx.y * 128;
  const int bn   = blockIdx.x * 128;
  const int lane = t & 63;
  const int w    = t >> 6, wm = w >> 1, wn = w & 1;
  const int quad = lane >> 4, l15 = lane & 15;

  f32x4 acc[4][4];
#pragma unroll
  for (int i = 0; i < 4; i++)
#pragma unroll
    for (int j = 0; j < 4; j++) acc[i][j] = (f32x4){0.f, 0.f, 0.f, 0.f};

  const ushort* AhiB = Ahi + (size_t)bm * K;
  const ushort* AloB = ALO ? (Alo + (size_t)bm * K) : nullptr;
  const ushort* BhB  = Wh  + (size_t)bn * K;

  for (int k0 = 0; k0 < K; k0 += 64) {
#pragma unroll
    for (int i = 0; i < 4; i++) {
      int idx = i * 256 + t;
      int row = idx >> 3, c = idx & 7;
      int k8  = c ^ (row & 7);
      size_t off = (size_t)row * K + k0 + k8 * 8;
      ((uint4*)AhiS)[idx] = *(const uint4*)(AhiB + off);
      if (ALO) ((uint4*)AloS)[idx] = *(const uint4*)(AloB + off);
      ((uint4*)BhS)[idx]  = *(const uint4*)(BhB + off);
    }
    __syncthreads();
#pragma unroll
    for (int ks = 0; ks < 2; ks++) {
      f16x8 ah[4], al[4], bh[4];
#pragma unroll
      for (int i = 0; i < 4; i++) {
        int row = wm * 64 + i * 16 + l15;
        int k8  = ks * 4 + quad;
        int ci  = k8 ^ (row & 7);
        ah[i] = ((const f16x8*)AhiS)[row * 8 + ci];
        if (ALO) al[i] = ((const f16x8*)AloS)[row * 8 + ci];
        int nrow = wn * 64 + i * 16 + l15;
        int cj   = k8 ^ (nrow & 7);
        bh[i] = ((const f16x8*)BhS)[nrow * 8 + cj];
      }
#pragma unroll
      for (int i = 0; i < 4; i++)
#pragma unroll
        for (int j = 0; j < 4; j++) {
          if (ALO) acc[i][j] = __builtin_amdgcn_mfma_f32_16x16x32_f16(al[i], bh[j], acc[i][j], 0, 0, 0);
          acc[i][j] = __builtin_amdgcn_mfma_f32_16x16x32_f16(ah[i], bh[j], acc[i][j], 0, 0, 0);
        }
    }
    __syncthreads();
  }

  float bv[4], scv[4], shv[4];
#pragma unroll
  for (int j = 0; j < 4; j++) {
    int col = bn + wn*64 + j*16 + l15;
    if (BIAS)    bv[j]  = bias[col];
    if (RESIDBN) { scv[j] = rsc[col]; shv[j] = rsh[col]; }
  }
  float sj[4] = {0.f,0.f,0.f,0.f}, qj[4] = {0.f,0.f,0.f,0.f};
#pragma unroll
  for (int i = 0; i < 4; i++) {
#pragma unroll
    for (int r = 0; r < 4; r++) {
      int row = bm + wm*64 + i*16 + quad*4 + r;
#pragma unroll
      for (int j = 0; j < 4; j++) {
        int col = bn + wn*64 + j*16 + l15;
        float v = acc[i][j][r];
        if (BIAS)    v += bv[j];
        if (RELU)    v = fmaxf(v, 0.f);
        if (RESIDBN) v += fmaf(residf[(size_t)row * Ntot + col], scv[j], shv[j]);
        if (OUTQKV) {
          if (bn < 256) {            // Q (pre-scaled) and K -> single fp16
            C16[(size_t)row * 256 + col] = f2h_bits(v);
          } else {                   // V -> fp16 hi/lo
            ushort hi, lo; splith(v, hi, lo);
            Chl_hi[(size_t)row * 128 + (col - 256)] = hi;
            Chl_lo[(size_t)row * 128 + (col - 256)] = lo;
          }
        }
        if (OUT16) C16[(size_t)row * Ntot + col] = f2h_bits(v);
        if (OUTHL) {
          ushort hi, lo; splith(v, hi, lo);
          Chl_hi[(size_t)row * Ntot + col] = hi;
          Chl_lo[(size_t)row * Ntot + col] = lo;
        }
        if (OUTF32) Cf[(size_t)row * Ntot + col] = v;
        if (STATS) { sj[j] += v; qj[j] = fmaf(v, v, qj[j]); }
      }
    }
  }
  if (STATS) {
#pragma unroll
    for (int j = 0; j < 4; j++) {
      sj[j] += __shfl_xor(sj[j], 16); sj[j] += __shfl_xor(sj[j], 32);
      qj[j] += __shfl_xor(qj[j], 16); qj[j] += __shfl_xor(qj[j], 32);
    }
    float* ssum = (float*)AhiS;     // safe: k-loop ended with barrier
    float* ssq  = ssum + 128;
    if (t < 128) { ssum[t] = 0.f; ssq[t] = 0.f; }
    __syncthreads();
    if (quad == 0) {
#pragma unroll
      for (int j = 0; j < 4; j++) {
        int col = wn*64 + j*16 + l15;
        atomicAdd(&ssum[col], sj[j]);
        atomicAdd(&ssq[col],  qj[j]);
      }
    }
    __syncthreads();
    if (t < 128) {
      psum[blockIdx.y * 128 + t] = ssum[t];
      psq [blockIdx.y * 128 + t] = ssq[t];
    }
  }
}

// ---------------- MFMA fused attention (fp16 inputs, zero-conversion staging) ----------------
// qk: [row][256] fp16 (cols 0-127 Q pre-scaled by 0.25*log2e, 128-255 K)
// vh/vl: [row][128] fp16 hi/lo.  hd out: [row][128] single fp16.
__global__ __launch_bounds__(256) void attn_kernel(const ushort* __restrict__ qk,
    const ushort* __restrict__ vh, const ushort* __restrict__ vl,
    ushort* __restrict__ hd)
{
  __shared__ __align__(16) _Float16 Ksh[208*24];    // [key][kd], pitch 24 (16B-aligned rows)
  __shared__ __align__(16) _Float16 VTh[16*216];    // V^T hi [kd][key], pitch 216
  __shared__ __align__(16) _Float16 VTl[16*216];    // V^T lo
  const int b  = blockIdx.x >> 3;
  const int hh = blockIdx.x & 7;
  const int t  = threadIdx.x;
  const size_t rb = (size_t)b * N_;

  // ---- stage K: straight ushort copy, 16B chunks; zero pad rows 200..207 ----
  for (int i = t; i < 208*2; i += 256) {
    int n = i >> 1, half = i & 1;
    uint4 kv = {0u, 0u, 0u, 0u};
    if (n < N_) kv = *(const uint4*)(qk + (rb + n)*256 + 128 + hh*16 + half*8);
    *(uint4*)&Ksh[n*24 + half*8] = kv;
  }
  // ---- stage V^T hi/lo: straight copy with transpose; zero pad cols 200..207 ----
  for (int i = t; i < 16*104; i += 256) {
    int kd = i & 15, n2 = i >> 4;
    int n0 = 2*n2, n1 = n0 + 1;
    ushort a0 = 0, a1 = 0, c0 = 0, c1 = 0;
    if (n0 < N_) { a0 = vh[(rb + n0)*128 + hh*16 + kd]; c0 = vl[(rb + n0)*128 + hh*16 + kd]; }
    if (n1 < N_) { a1 = vh[(rb + n1)*128 + hh*16 + kd]; c1 = vl[(rb + n1)*128 + hh*16 + kd]; }
    *(uint*)&VTh[kd*216 + n0] = (uint)a0 | ((uint)a1 << 16);
    *(uint*)&VTl[kd*216 + n0] = (uint)c0 | ((uint)c1 << 16);
  }
  __syncthreads();

  const int lane = t & 63;
  const int w    = t >> 6;
  const int l15  = lane & 15;
  const int g    = lane >> 4;

  for (int qt = w; qt < 13; qt += 4) {
    int qr  = qt*16 + l15;                 // query row in [0,208)
    int qrc = qr < N_ ? qr : N_-1;         // clamp pad rows (results discarded)
    f16x4 bq = *(const f16x4*)(qk + (rb + qrc)*256 + hh*16 + g*4);

    // S^T tiles: ct[kt] holds scores (log2-units) for keys kt*16+g*4+r, query q=l15
    f32x4 ct[13];
#pragma unroll
    for (int kt = 0; kt < 13; kt++) {
      f16x4 ak = *(const f16x4*)&Ksh[(kt*16 + l15)*24 + g*4];
      ct[kt] = __builtin_amdgcn_mfma_f32_16x16x16f16(ak, bq, (f32x4){0.f,0.f,0.f,0.f}, 0, 0, 0);
    }
    // mask pad keys (192+g*4+r >= 200)
#pragma unroll
    for (int r = 0; r < 4; r++)
      if (g*4 + r >= 8) ct[12][r] = -1e30f;

    // row max over 13 tiles then across lane groups
    float m0 = -1e30f, m1 = -1e30f;
#pragma unroll
    for (int kt = 0; kt < 13; kt++) {
      m0 = fmaxf(m0, fmaxf(ct[kt][0], ct[kt][1]));
      m1 = fmaxf(m1, fmaxf(ct[kt][2], ct[kt][3]));
    }
    float m = fmaxf(m0, m1);
    m = fmaxf(m, __shfl_xor(m, 16));
    m = fmaxf(m, __shfl_xor(m, 32));

    // exp2 + row sum
    float la0 = 0.f, la1 = 0.f, la2 = 0.f, la3 = 0.f;
#pragma unroll
    for (int kt = 0; kt < 13; kt++) {
      float p0 = __builtin_amdgcn_exp2f(ct[kt][0] - m);
      float p1 = __builtin_amdgcn_exp2f(ct[kt][1] - m);
      float p2 = __builtin_amdgcn_exp2f(ct[kt][2] - m);
      float p3 = __builtin_amdgcn_exp2f(ct[kt][3] - m);
      la0 += p0; la1 += p1; la2 += p2; la3 += p3;
      ct[kt][0] = p0; ct[kt][1] = p1; ct[kt][2] = p2; ct[kt][3] = p3;
    }
    float l = (la0 + la1) + (la2 + la3);
    l += __shfl_xor(l, 16);
    l += __shfl_xor(l, 32);

    // O^T = V^T(hi) P^T + V^T(lo) P^T
    f32x4 och = {0.f,0.f,0.f,0.f}, ocl = {0.f,0.f,0.f,0.f};
#pragma unroll
    for (int kt = 0; kt < 13; kt++) {
      f16x4 pt = { (_Float16)ct[kt][0], (_Float16)ct[kt][1],
                   (_Float16)ct[kt][2], (_Float16)ct[kt][3] };
      f16x4 avh = *(const f16x4*)&VTh[l15*216 + kt*16 + g*4];
      f16x4 avl = *(const f16x4*)&VTl[l15*216 + kt*16 + g*4];
      och = __builtin_amdgcn_mfma_f32_16x16x16f16(avh, pt, och, 0, 0, 0);
      ocl = __builtin_amdgcn_mfma_f32_16x16x16f16(avl, pt, ocl, 0, 0, 0);
    }

    if (qr < N_) {
      float inv = __builtin_amdgcn_rcpf(l);
      ushort o16[4];
#pragma unroll
      for (int r = 0; r < 4; r++) o16[r] = f2h_bits((och[r] + ocl[r]) * inv);
      uint2 p;
      p.x = (uint)o16[0] | ((uint)o16[1] << 16);
      p.y = (uint)o16[2] | ((uint)o16[3] << 16);
      *(uint2*)(hd + (rb + qr)*128 + hh*16 + g*4) = p;
    }
  }
}

// ---------------- BN finalize: PARALLEL (block=channel, wave reduce 400 partials) ----------------
__global__ __launch_bounds__(64) void bn_finalize(const float* __restrict__ psum,
    const float* __restrict__ psq, const float* __restrict__ g,
    const float* __restrict__ bta, float* __restrict__ scale, float* __restrict__ shift)
{
  int c = blockIdx.x;        // 0..127
  int i = threadIdx.x;       // 0..63
  float s = 0.f, q = 0.f;
  for (int r = i; r < 400; r += 64) { s += psum[r*128 + c]; q += psq[r*128 + c]; }
#pragma unroll
  for (int d = 32; d > 0; d >>= 1) { s += __shfl_down(s, d); q += __shfl_down(q, d); }
  if (i == 0) {
    const float invM = 1.f / 51200.f;
    float m  = s * invM;
    float v  = fmaf(q, invM, -m * m);
    float r  = rsqrtf(v + 1e-5f);
    float sc = r * g[c];
    scale[c] = sc;
    shift[c] = fmaf(-m, sc, bta[c]);
  }
}

// ---------------- final BN apply + per-batch mean (fused) ----------------
__global__ __launch_bounds__(128) void bn_mean_final(float* __restrict__ hp,
    const float* __restrict__ scale, const float* __restrict__ shift,
    float* __restrict__ mout)
{
  int b = blockIdx.x, d = threadIdx.x;
  float sc = scale[d], sh = shift[d];
  float* p = hp + (size_t)b * N_ * D_ + d;
  float s = 0.f;
  for (int n = 0; n < N_; n++) {
    float v = fmaf(p[n * D_], sc, sh);
    p[n * D_] = v;
    s += v;
  }
  mout[b * D_ + d] = s * (1.f / N_);
}

extern "C" void kernel_launch(void* const* d_in, const int* in_sizes, int n_in,
                              void* d_out, int out_size, void* d_ws, size_t ws_size,
                              hipStream_t stream)
{
  const float* x    = (const float*)d_in[0];
  const float* Wemb = (const float*)d_in[1];
  const float* bemb = (const float*)d_in[2];
  const float* Wq   = (const float*)d_in[3];
  const float* Wk   = (const float*)d_in[4];
  const float* Wv   = (const float*)d_in[5];
  const float* Wo   = (const float*)d_in[6];
  const float* bn1g = (const float*)d_in[7];
  const float* bn1b = (const float*)d_in[8];
  const float* W1   = (const float*)d_in[9];
  const float* b1   = (const float*)d_in[10];
  const float* W2   = (const float*)d_in[11];
  const float* b2   = (const float*)d_in[12];
  const float* bn2g = (const float*)d_in[13];
  const float* bn2b = (const float*)d_in[14];
  float* out = (float*)d_out;

  // rolling pre-BN residual state hp lives in d_out[0:BND]
  float* hp = out;

  char* wsb = (char*)d_ws;
  ushort* h_hi  = (ushort*)wsb;                     // 13,107,200 B (fp16 hi)
  ushort* h_lo  = (ushort*)(wsb + 13107200);        // 13,107,200 B (fp16 lo)
  char*   phase = wsb + 26214400;                   // 65,536,000 B union
  ushort* qkq   = (ushort*)phase;                   //   attn: 26,214,400 B (Q|K fp16)
  ushort* vhh   = (ushort*)(phase + 26214400);      //   attn: 13,107,200 B (V hi)
  ushort* vll   = (ushort*)(phase + 39321600);      //   attn: 13,107,200 B (V lo)
  ushort* hd    = (ushort*)(phase + 52428800);      //   attn: 13,107,200 B (heads fp16)
  ushort* hid   = (ushort*)phase;                   //   ffn: 52,428,800 B (hidden fp16)
  char*   wp    = wsb + 91750400;
  ushort* woT   = (ushort*)wp;                      // 98,304 B
  ushort* w2T   = (ushort*)(wp + 98304);            // 393,216 B
  ushort* fqkvw = (ushort*)(wp + 491520);           // 98,304 B
  ushort* fw1w  = (ushort*)(wp + 589824);           // 131,072 B
  float*  fqkv_b = (float*)(wp + 720896);           // 1,536 B
  float*  fw1_b  = (float*)(wp + 722432);           // 2,048 B
  float*  psum   = (float*)(wp + 724480);           // 204,800 B
  float*  psq    = (float*)(wp + 929280);           // 204,800 B
  float*  sc_a   = (float*)(wp + 1134080);
  float*  sh_a   = (float*)(wp + 1134592);
  float*  sc_b   = (float*)(wp + 1135104);
  float*  sh_b   = (float*)(wp + 1135616);

  embed_kernel<<<6400, 256, 0, stream>>>(x, Wemb, bemb, hp, h_hi, h_lo);
  t_wo<<<192, 256, 0, stream>>>(Wo, woT);
  t_w2<<<768, 256, 0, stream>>>(W2, w2T);
  init_scales<<<1, 128, 0, stream>>>(sc_b, sh_b);

  for (int l = 0; l < L_; l++) {
    // fold BN(prev/identity) into QKV weights (Q pre-scaled)
    fold_qkv<<<384, 128, 0, stream>>>(Wq + l*16384, Wk + l*16384, Wv + l*16384,
                                      sc_b, sh_b, fqkvw, fqkv_b);
    // QKV projection -> qk fp16 [row][256] + V hi/lo [row][128]
    gemm_mfma<128, true, true, false, false, true, false, false, false, false>
        <<<dim3(3, 400), 256, 0, stream>>>(
        h_hi, h_lo, fqkvw, fqkv_b, nullptr, nullptr, nullptr,
        nullptr, qkq, vhh, vll, nullptr, nullptr, 384);
    // attention -> heads fp16
    attn_kernel<<<B_ * H_, 256, 0, stream>>>(qkq, vhh, vll, hd);
    // out-proj (1 MFMA/acc) + BN-folded residual -> hp fp32 + h hi/lo + BN1 stats
    gemm_mfma<128, false, false, false, true, false, false, true, true, true>
        <<<dim3(1, 400), 256, 0, stream>>>(
        hd, nullptr, woT + l*16384, nullptr, hp, sc_b, sh_b,
        hp, nullptr, h_hi, h_lo, psum, psq, 128);
    bn_finalize<<<128, 64, 0, stream>>>(psum, psq, bn1g + l*128, bn1b + l*128, sc_a, sh_a);
    // fold BN1 into W1
    fold_w1<<<512, 128, 0, stream>>>(W1 + l*65536, b1 + l*512, sc_a, sh_a, fw1w, fw1_b);
    // FFN1 + folded bias + relu -> hidden single fp16
    gemm_mfma<128, true, true, true, false, false, true, false, false, false>
        <<<dim3(4, 400), 256, 0, stream>>>(
        h_hi, h_lo, fw1w, fw1_b, nullptr, nullptr, nullptr,
        nullptr, hid, nullptr, nullptr, nullptr, nullptr, 512);
    // FFN2 (1 MFMA/acc) + bias + BN1-folded residual -> hp fp32 + h hi/lo + BN2 stats
    gemm_mfma<512, false, true, false, true, false, false, true, true, true>
        <<<dim3(1, 400), 256, 0, stream>>>(
        hid, nullptr, w2T + l*65536, b2 + l*128, hp, sc_a, sh_a,
        hp, nullptr, h_hi, h_lo, psum, psq, 128);
    bn_finalize<<<128, 64, 0, stream>>>(psum, psq, bn2g + l*128, bn2b + l*128, sc_b, sh_b);
  }

  bn_mean_final<<<B_, 128, 0, stream>>>(hp, sc_b, sh_b, out + BND);
}